// Round 13
// baseline (584.765 us; speedup 1.0000x reference)
//
#include <hip/hip_runtime.h>

// Problem constants (B=2, H=16, L=2048, D=64 — fixed by the reference setup).
#define BH   32
#define LSEQ 2048
#define DDIM 64
#define ERRC 1e-12f

typedef __attribute__((ext_vector_type(8)))  short bf16x8;
typedef __attribute__((ext_vector_type(4)))  float floatx4;
typedef __attribute__((ext_vector_type(4)))  unsigned short ushort4v;

// float -> bf16 round-to-nearest-even (inputs are finite, no NaN handling needed)
__device__ __forceinline__ unsigned short f2bf(float f) {
    unsigned u = __float_as_uint(f);
    u = u + 0x7FFFu + ((u >> 16) & 1u);
    return (unsigned short)(u >> 16);
}

__device__ __forceinline__ bf16x8 pack8s(const float* __restrict__ p, float w) {
    const floatx4* pv = (const floatx4*)p;
    floatx4 x = pv[0], y = pv[1];
    bf16x8 r;
    r[0] = (short)f2bf(x[0] * w); r[1] = (short)f2bf(x[1] * w);
    r[2] = (short)f2bf(x[2] * w); r[3] = (short)f2bf(x[3] * w);
    r[4] = (short)f2bf(y[0] * w); r[5] = (short)f2bf(y[1] * w);
    r[6] = (short)f2bf(y[2] * w); r[7] = (short)f2bf(y[3] * w);
    return r;
}

// Prep (round-12 verbatim, harness-passed):
//   ks = bf16(k*sqrt(src+err)) row-major (B operand, read once per wave);
//   kd = bf16(k*sqrt(dest+err)) in MFMA-TILE layout: tile jt = 1024 contiguous
//   ush; lane ln's lo-fragment at jt*1024 + ln*8, hi at +512.
__global__ __launch_bounds__(256) void prep_scaled2(const float* __restrict__ k,
                                                    const float* __restrict__ src,
                                                    const float* __restrict__ dest,
                                                    unsigned short* __restrict__ ks,
                                                    unsigned short* __restrict__ kd) {
    int idx4 = blockIdx.x * 256 + threadIdx.x;
    int row  = idx4 >> 4;                     // global row: bh*2048 + r
    int d    = (idx4 & 15) * 4;               // element offset 0..60
    float s = sqrtf(src[row] + ERRC);
    float dd = sqrtf(dest[row] + ERRC);
    floatx4 v = ((const floatx4*)k)[idx4];
    ushort4v os, od;
#pragma unroll
    for (int r = 0; r < 4; ++r) { os[r] = f2bf(v[r] * s); od[r] = f2bf(v[r] * dd); }
    ((ushort4v*)ks)[idx4] = os;               // row-major
    const int jt   = row >> 4;                // global tile (bh*128 + local)
    const int l16  = row & 15;
    const int half = d >> 5;
    const int q    = (d & 31) >> 3;
    const long off = (long)jt * 1024 + half * 512 + (q * 16 + l16) * 8 + (d & 7);
    *(ushort4v*)(kd + off) = od;
}

// Async global->LDS stage, 16B per lane (1KB per call per wave).
// LDS dest is wave-uniform base + lane*16 (HW rule); global src is per-lane.
__device__ __forceinline__ void gll16(const unsigned short* g, unsigned short* l) {
    __builtin_amdgcn_global_load_lds(
        (const __attribute__((address_space(1))) unsigned int*)(const void*)g,
        (__attribute__((address_space(3))) unsigned int*)(void*)l, 16, 0, 0);
}

// One wave = one 16-column i-tile; the 4 waves of a block share bh and stream
// THE SAME kd tiles — so each 8KB j-group (4 tiles) is staged ONCE per block
// into double-buffered LDS via async global_load_lds (2 instr/wave/group),
// cutting global read requests 4x vs r12. __syncthreads() at group end drains
// vmcnt (staging complete) and swaps buffers (m97-proven structure).
// Swapped MFMA: D = kd_tile(j rows) . ks_rows(i)^T -> D[m=j][n=i],
// C/D: col(l16)=i, row(q*4+r)=j -> each lane holds 4 CONSECUTIVE j per tile.
__global__ __launch_bounds__(256, 4) void mha_fused9(const unsigned short* __restrict__ kdt,
                                                     const unsigned short* __restrict__ ks,
                                                     float* __restrict__ out) {
    __shared__ __align__(16) unsigned short stage[2][4096];   // 2 x 8KB (4 tiles)
    const int tid  = threadIdx.x;
    const int wave = tid >> 6;
    const int lane = tid & 63;
    const int q    = lane >> 4;
    const int l16  = lane & 15;
    // bh in low bits: same-bh blocks are 32 apart -> same XCD under mod-8 dispatch.
    const int bh = blockIdx.x & 31;
    const int ib = blockIdx.x >> 5;           // 0..31
    const int i0 = (ib * 4 + wave) * 16;      // this wave's 16-column (i) tile
    const int bhL = bh * LSEQ;
    const unsigned short* kdb = kdt + (long)bh * (128 * 1024); // 128 tiles x 1024 ush

    // B operand: ks row i0+l16, held for the whole kernel
    const unsigned short* bp = ks + (long)(bhL + i0 + l16) * DDIM + q * 8;
    const bf16x8 blo = *(const bf16x8*)bp;
    const bf16x8 bhi = *(const bf16x8*)(bp + 32);

    float carry = 0.f;                        // running row sum for output row i0+l16
    const float c23 = 2.0f / 3.0f;
    float* orow = out + (long)(bhL + i0 + l16) * LSEQ + q * 4;

    // stage group 0 into buffer 0: wave w stages tile w (2KB = two 1KB calls)
    {
        const unsigned short* g0 = kdb + wave * 1024 + lane * 8;
        unsigned short* l0 = &stage[0][wave * 1024];
        gll16(g0, l0);
        gll16(g0 + 512, l0 + 512);
    }
    __syncthreads();                          // drains vmcnt: buffer 0 ready

    int cur = 0;
    for (int g = 0; g < 32; ++g) {
        const int j0 = g << 6;

        // issue async stage of the NEXT group into the other buffer
        const int gn = (g < 31) ? (g + 1) : 0;
        {
            const unsigned short* gs = kdb + (long)(gn * 4 + wave) * 1024 + lane * 8;
            unsigned short* ld = &stage[cur ^ 1][wave * 1024];
            gll16(gs, ld);
            gll16(gs + 512, ld + 512);
        }

        // A fragments from LDS (fragment-ordered: lane*16B within each 2KB tile)
        floatx4 acc[4];
#pragma unroll
        for (int t = 0; t < 4; ++t) {
            const unsigned short* tb = &stage[cur][t * 1024 + lane * 8];
            bf16x8 alo = *(const bf16x8*)tb;
            bf16x8 ahi = *(const bf16x8*)(tb + 512);
            floatx4 z4 = {0.f, 0.f, 0.f, 0.f};
            z4 = __builtin_amdgcn_mfma_f32_16x16x32_bf16(alo, blo, z4, 0, 0, 0);
            acc[t] = __builtin_amdgcn_mfma_f32_16x16x32_bf16(ahi, bhi, z4, 0, 0, 0);
        }

        // a3 = exp2(log2(relu(a1)+err) * 2/3) — 16 independent elements
        float u[4][4];
#pragma unroll
        for (int t = 0; t < 4; ++t)
#pragma unroll
            for (int r = 0; r < 4; ++r) {
                float v = fmaxf(acc[t][r], 0.f) + ERRC;
                u[t][r] = exp2f(c23 * __log2f(v));
            }

        if (j0 + 64 <= i0) {
            // all 4 tiles fully below the diagonal: only the total feeds carry
            float s = 0.f;
#pragma unroll
            for (int t = 0; t < 4; ++t)
                s += (u[t][0] + u[t][1]) + (u[t][2] + u[t][3]);
            float s1 = s + __shfl_xor(s, 16, 64);
            carry += s1 + __shfl_xor(s1, 32, 64);
            const floatx4 z = {0.f, 0.f, 0.f, 0.f};
#pragma unroll
            for (int t = 0; t < 4; ++t)
                *(floatx4*)(orow + j0 + 16 * t) = z;
        } else {
#pragma unroll
            for (int t = 0; t < 4; ++t) {
                const int jt0 = j0 + 16 * t;
                if (jt0 + 16 <= i0) {
                    // fully masked tile: total only
                    float s = (u[t][0] + u[t][1]) + (u[t][2] + u[t][3]);
                    float s1 = s + __shfl_xor(s, 16, 64);
                    carry += s1 + __shfl_xor(s1, 32, 64);
                    const floatx4 z = {0.f, 0.f, 0.f, 0.f};
                    *(floatx4*)(orow + jt0) = z;
                } else {
                    // in-lane inclusive prefix over this lane's 4 consecutive j
                    u[t][1] += u[t][0];
                    u[t][2] += u[t][1];
                    u[t][3] += u[t][2];
                    const float Sg  = u[t][3];
                    const float x16 = __shfl_xor(Sg, 16, 64);
                    const float s1  = Sg + x16;
                    const float x32 = __shfl_xor(s1, 32, 64);
                    // exclusive prefix over the 4 q-chunks + running carry
                    const float E = ((q & 1) ? x16 : 0.f) + ((q & 2) ? x32 : 0.f) + carry;
                    carry += s1 + x32;        // tile total — identical across the group
                    floatx4 o;
                    if (jt0 == i0) {          // the single mixed (diagonal) tile
#pragma unroll
                        for (int r = 0; r < 4; ++r)
                            o[r] = ((q * 4 + r) >= l16) ? (u[t][r] + E) : 0.f;
                    } else {                  // fully above diagonal
#pragma unroll
                        for (int r = 0; r < 4; ++r)
                            o[r] = u[t][r] + E;
                    }
                    *(floatx4*)(orow + jt0) = o;
                }
            }
        }

        __syncthreads();                      // drain staging + swap barrier
        cur ^= 1;
    }
}

// ---------------------------------------------------------------------------
// Fallback (workspace too small): single-pass kernel reading raw fp32 k
// (round-3 structure, harness-proven). Correct but slower.
// ---------------------------------------------------------------------------
__device__ __forceinline__ void load_row16_raw(const float* __restrict__ kp, long base, int row,
                                               int q, const float* __restrict__ w, int bhL,
                                               bf16x8& lo, bf16x8& hi) {
    const float* p = kp + base + (long)row * DDIM + q * 8;
    float s = sqrtf(w[bhL + row] + ERRC);
    lo = pack8s(p, s);
    hi = pack8s(p + 32, s);
}

__global__ __launch_bounds__(256, 4) void mha_raw(const float* __restrict__ kp,
                                                  const float* __restrict__ src,
                                                  const float* __restrict__ dest,
                                                  float* __restrict__ out) {
    const int tid  = threadIdx.x;
    const int wave = tid >> 6;
    const int lane = tid & 63;
    const int q    = lane >> 4;
    const int l16  = lane & 15;
    const int bh = blockIdx.x & 31;
    const int ib = blockIdx.x >> 5;
    const int i0 = (ib * 4 + wave) * 16;
    const int bhL = bh * LSEQ;
    const long base = (long)bh * LSEQ * DDIM;

    bf16x8 blo, bhi;
    load_row16_raw(kp, base, i0 + l16, q, src, bhL, blo, bhi);

    float carry = 0.f;
    const float c23 = 2.0f / 3.0f;

    bf16x8 aLo[4], aHi[4];
#pragma unroll
    for (int t = 0; t < 4; ++t)
        load_row16_raw(kp, base, 16 * t + l16, q, dest, bhL, aLo[t], aHi[t]);

    float* orow = out + (long)(bhL + i0 + l16) * LSEQ + q * 4;

    for (int it = 0; it < 32; ++it) {
        const int j0 = it << 6;
        bf16x8 nLo[4], nHi[4];
        const int jn = (it < 31) ? (j0 + 64) : 0;
#pragma unroll
        for (int t = 0; t < 4; ++t)
            load_row16_raw(kp, base, jn + 16 * t + l16, q, dest, bhL, nLo[t], nHi[t]);

        floatx4 acc[4];
#pragma unroll
        for (int t = 0; t < 4; ++t) {
            floatx4 z4 = {0.f, 0.f, 0.f, 0.f};
            z4 = __builtin_amdgcn_mfma_f32_16x16x32_bf16(aLo[t], blo, z4, 0, 0, 0);
            acc[t] = __builtin_amdgcn_mfma_f32_16x16x32_bf16(aHi[t], bhi, z4, 0, 0, 0);
        }

        float uu[4][4];
#pragma unroll
        for (int t = 0; t < 4; ++t)
#pragma unroll
            for (int r = 0; r < 4; ++r) {
                float v = fmaxf(acc[t][r], 0.f) + ERRC;
                uu[t][r] = exp2f(c23 * __log2f(v));
            }

#pragma unroll
        for (int t = 0; t < 4; ++t) {
            const int jt0 = j0 + 16 * t;
            if (jt0 + 16 <= i0) {
                float s = (uu[t][0] + uu[t][1]) + (uu[t][2] + uu[t][3]);
                float s1 = s + __shfl_xor(s, 16, 64);
                carry += s1 + __shfl_xor(s1, 32, 64);
                const floatx4 z = {0.f, 0.f, 0.f, 0.f};
                *(floatx4*)(orow + jt0) = z;
            } else {
                uu[t][1] += uu[t][0];
                uu[t][2] += uu[t][1];
                uu[t][3] += uu[t][2];
                const float Sg  = uu[t][3];
                const float x16 = __shfl_xor(Sg, 16, 64);
                const float s1  = Sg + x16;
                const float x32 = __shfl_xor(s1, 32, 64);
                const float E = ((q & 1) ? x16 : 0.f) + ((q & 2) ? x32 : 0.f) + carry;
                carry += s1 + x32;
                floatx4 o;
                if (jt0 == i0) {
#pragma unroll
                    for (int r = 0; r < 4; ++r)
                        o[r] = ((q * 4 + r) >= l16) ? (uu[t][r] + E) : 0.f;
                } else {
#pragma unroll
                    for (int r = 0; r < 4; ++r)
                        o[r] = uu[t][r] + E;
                }
                *(floatx4*)(orow + jt0) = o;
            }
        }

#pragma unroll
        for (int t = 0; t < 4; ++t) { aLo[t] = nLo[t]; aHi[t] = nHi[t]; }
    }
}

extern "C" void kernel_launch(void* const* d_in, const int* in_sizes, int n_in,
                              void* d_out, int out_size, void* d_ws, size_t ws_size,
                              hipStream_t stream) {
    const float* k    = (const float*)d_in[0];
    const float* src  = (const float*)d_in[1];
    const float* dest = (const float*)d_in[2];
    float* out = (float*)d_out;

    const size_t half = (size_t)BH * LSEQ * DDIM * sizeof(unsigned short); // 8 MiB
    if (ws_size >= 2 * half) {
        unsigned short* ks = (unsigned short*)d_ws;
        unsigned short* kd = (unsigned short*)((char*)d_ws + half);        // tiled layout
        prep_scaled2<<<dim3(4096), dim3(256), 0, stream>>>(k, src, dest, ks, kd);
        mha_fused9<<<dim3(1024), dim3(256), 0, stream>>>(kd, ks, out);
    } else {
        mha_raw<<<dim3(1024), dim3(256), 0, stream>>>(k, src, dest, out);
    }
}